// Round 4
// baseline (89.007 us; speedup 1.0000x reference)
//
#include <hip/hip_runtime.h>
#include <hip/hip_cooperative_groups.h>
#include <math.h>

namespace cg = cooperative_groups;

// SelfRouting2d — collapsed math:
//   softmax over K of K-identical logits == 1/K exactly -> W2, b2 cancel.
//   out[b,k,u] = (1/S[b]) * sum_i W1[k,u,i] * z[b,i]
//   z[b,i] = sum_n a[b,n]*x[b,i,n],  a[b,n]=||x[b,:,n]||_2,  S[b]=sum_n a[b,n]
//
// Single cooperative dispatch: part A = per-(b,chunk) z/s partials (x read from
// HBM exactly once, float4, LDS-staged with XOR quad swizzle); grid.sync();
// part B = 512 blocks finalize (b,g) with fully-coalesced W1 reads.

#define BB 64
#define IN_UNITS 64
#define NCAPS 2048
#define OUT_PER_B 512   // K=32 * U=16
#define CHUNKS 16
#define TILE_N 128      // n per block in part A

__global__ __launch_bounds__(256, 4) void sr_fused(
    const float* __restrict__ x, const float* __restrict__ W1,
    float* __restrict__ out, float* __restrict__ z_part, float* __restrict__ s_part)
{
  __shared__ __align__(16) float xt[IN_UNITS][TILE_N];  // 32KB, swizzled [i][nquad^..]
  __shared__ float4 ssqp[8][32];                        // 4KB per-(ih,q) ssq partials
  __shared__ __align__(16) float a_lds[TILE_N];
  __shared__ float ztmp[4][IN_UNITS];
  __shared__ float swave[2];
  __shared__ __align__(16) float z_l[IN_UNITS];
  __shared__ float sinv_l;

  const int bid   = blockIdx.x;
  const int b     = bid >> 4;          // CHUNKS = 16
  const int chunk = bid & 15;
  const int n0    = chunk * TILE_N;
  const int t     = threadIdx.x;

  const int q  = t & 31;               // quad within row (32 quads = 128 floats)
  const int ih = t >> 5;               // 0..7 -> owns rows ih*8 .. ih*8+7

  // ---- part A phase 1: single coalesced float4 read of the 32KB tile + ssq
  const float* xb = x + (size_t)b * IN_UNITS * NCAPS + n0;
  float4 ssq4 = make_float4(0.f, 0.f, 0.f, 0.f);
  #pragma unroll
  for (int j = 0; j < 8; ++j) {
    const int r = ih * 8 + j;
    float4 xv = reinterpret_cast<const float4*>(xb + (size_t)r * NCAPS)[q];
    ssq4.x = fmaf(xv.x, xv.x, ssq4.x);
    ssq4.y = fmaf(xv.y, xv.y, ssq4.y);
    ssq4.z = fmaf(xv.z, xv.z, ssq4.z);
    ssq4.w = fmaf(xv.w, xv.w, ssq4.w);
    reinterpret_cast<float4*>(&xt[r][0])[q ^ (r & 7)] = xv;  // XOR swizzle
  }
  ssqp[ih][q] = ssq4;
  __syncthreads();

  // a[n] = sqrt(sum of 8 ih-partials); threads 0..127 own one n each
  float a = 0.f;
  if (t < TILE_N) {
    const int nq = t >> 2, c = t & 3;
    float ss = 0.f;
    #pragma unroll
    for (int k = 0; k < 8; ++k)
      ss += reinterpret_cast<const float*>(&ssqp[k][nq])[c];  // bank = t%32
    a = sqrtf(ss);
    a_lds[t] = a;
  }
  float s = a;
  #pragma unroll
  for (int off = 32; off > 0; off >>= 1) s += __shfl_down(s, off, 64);
  if ((t & 63) == 0 && t < 128) swave[t >> 6] = s;
  __syncthreads();
  if (t == 0) s_part[b * CHUNKS + chunk] = swave[0] + swave[1];

  // ---- part A phase 2: z partial from LDS (conflict-free via swizzle)
  const int i  = t & 63;
  const int tg = t >> 6;               // owns quads tg*8 .. tg*8+7
  const float4* a4 = reinterpret_cast<const float4*>(a_lds);
  float acc = 0.f;
  #pragma unroll
  for (int m = 0; m < 8; ++m) {
    const int qq = tg * 8 + m;
    float4 xv = reinterpret_cast<const float4*>(&xt[i][0])[qq ^ (i & 7)];
    float4 av = a4[qq];                // uniform addr -> broadcast
    acc = fmaf(xv.x, av.x, acc);
    acc = fmaf(xv.y, av.y, acc);
    acc = fmaf(xv.z, av.z, acc);
    acc = fmaf(xv.w, av.w, acc);
  }
  ztmp[tg][i] = acc;
  __syncthreads();
  if (t < IN_UNITS) {
    z_part[((size_t)b * CHUNKS + chunk) * IN_UNITS + t] =
        ztmp[0][t] + ztmp[1][t] + ztmp[2][t] + ztmp[3][t];
  }

  // ---- grid-wide barrier: all z/s partials visible device-wide after this
  cg::this_grid().sync();

  // ---- part B: 512 blocks finalize; fb = bid>>3 is the batch, g = bid&7
  if (bid < BB * 8) {
    const int fb = bid >> 3;
    const int g  = bid & 7;
    if (t < IN_UNITS) {
      float zz = 0.f;
      #pragma unroll
      for (int c = 0; c < CHUNKS; ++c)
        zz += z_part[((size_t)fb * CHUNKS + c) * IN_UNITS + t];
      z_l[t] = zz;
    } else if (t == IN_UNITS) {
      float ssum = 0.f;
      #pragma unroll
      for (int c = 0; c < CHUNKS; ++c) ssum += s_part[fb * CHUNKS + c];
      sinv_l = 1.0f / ssum;
    }
    __syncthreads();

    // output j = g*64 + (t>>2); 4 threads/output -> W1 reads are contiguous
    // 64B lane stride (wave covers 4KB of W1 per instr, fully coalesced).
    const int jl   = t >> 2;
    const int part = t & 3;
    const int j    = g * 64 + jl;
    const float4* w4 = reinterpret_cast<const float4*>(W1 + (size_t)j * IN_UNITS + part * 16);
    const float4* z4 = reinterpret_cast<const float4*>(z_l) + part * 4;
    float oacc = 0.f;
    #pragma unroll
    for (int jj = 0; jj < 4; ++jj) {
      float4 wv = w4[jj];
      float4 zv = z4[jj];
      oacc = fmaf(wv.x, zv.x, oacc);
      oacc = fmaf(wv.y, zv.y, oacc);
      oacc = fmaf(wv.z, zv.z, oacc);
      oacc = fmaf(wv.w, zv.w, oacc);
    }
    oacc += __shfl_xor(oacc, 1);
    oacc += __shfl_xor(oacc, 2);
    if (part == 0) out[(size_t)fb * OUT_PER_B + j] = oacc * sinv_l;
  }
}

extern "C" void kernel_launch(void* const* d_in, const int* in_sizes, int n_in,
                              void* d_out, int out_size, void* d_ws, size_t ws_size,
                              hipStream_t stream) {
  const float* x  = (const float*)d_in[0];
  const float* W1 = (const float*)d_in[1];
  // d_in[2] (W2) and d_in[3] (b2) cancel exactly: softmax over the K axis of
  // K-identical logits is uniform 1/K regardless of logit values.
  float* out = (float*)d_out;

  float* z_part = (float*)d_ws;                              // 64*16*64 f32
  float* s_part = z_part + (size_t)BB * CHUNKS * IN_UNITS;   // 64*16 f32

  void* args[] = {(void*)&x, (void*)&W1, (void*)&out, (void*)&z_part, (void*)&s_part};
  hipLaunchCooperativeKernel((const void*)sr_fused, dim3(BB * CHUNKS), dim3(256),
                             args, 0, stream);
}